// Round 3
// baseline (5219.631 us; speedup 1.0000x reference)
//
#include <hip/hip_runtime.h>
#include <hip/hip_bf16.h>

typedef __attribute__((ext_vector_type(8))) short short8;
typedef __attribute__((ext_vector_type(4))) float float4v;

#define P 512
#define KF 64
#define NN 100000
#define NCHUNK 3125          // NN / 32
#define GRID_BIG 256
#define PART_STRIDE (4096 + 32768)

// workspace layout (float offsets)
#define WS_L      0
#define WS_LNEW   32768
#define WS_PSI    65536
#define WS_PINV   66048
#define WS_YY     66560
#define WS_M      67072
#define WS_IMINV  71168
#define WS_G      75264
#define WS_LT     79360      // LtermT [64][512]
#define WS_SCAL   112128     // [0]=A, [1]=sum(log Psi)
#define WS_BETA   112384     // bf16 [64][512]  (16384 float slots)
#define WS_PART   128768     // 256 * 36864
#define WS_YBT    9565952    // bf16 [100000][512]
#define WS_YB     35165952   // bf16 [512][100000]
#define WS_TOTAL_F 60765952ULL

__device__ inline unsigned short f2bf(float f) {
    unsigned int u = __float_as_uint(f);
    u = u + 0x7FFFu + ((u >> 16) & 1u);
    return (unsigned short)(u >> 16);
}

// ---------------- init: L = concat(L1,L2), Psi = concat(P1,P2) ----------------
__global__ void k_init(const float* __restrict__ l1, const float* __restrict__ l2,
                       const float* __restrict__ p1, const float* __restrict__ p2,
                       float* __restrict__ ws) {
    int i = blockIdx.x * 256 + threadIdx.x;
    if (i < 16384) ws[WS_L + i] = l1[i];
    else if (i < 32768) ws[WS_L + i] = l2[i - 16384];
    else if (i < 33280) {
        int j = i - 32768;
        ws[WS_PSI + j] = (j < 256) ? p1[j] : p2[j - 256];
    }
}

// ---------------- convert: y f32 -> y_bf (p-major) + y_bfT (n-major), yy_sum ----------------
__global__ __launch_bounds__(256) void k_convert(const float* __restrict__ y, float* __restrict__ ws) {
    __shared__ unsigned short tile[64][65];
    const int t = threadIdx.x;
    const int c0 = blockIdx.x * 64;
    const int p0 = blockIdx.y * 64;
    unsigned short* ybf = (unsigned short*)(ws + WS_YB);
    unsigned short* ybt = (unsigned short*)(ws + WS_YBT);

    const int r = t >> 2, seg = t & 3;
    const int c = c0 + seg * 16;
    float s = 0.f;
    if (c < NN) {
        const float* src = y + (size_t)(p0 + r) * NN + c;
        float v[16];
        #pragma unroll
        for (int i = 0; i < 16; i++) v[i] = src[i];
        unsigned short h[16];
        #pragma unroll
        for (int i = 0; i < 16; i++) { s = fmaf(v[i], v[i], s); h[i] = f2bf(v[i]); }
        short8 a0, a1;
        #pragma unroll
        for (int i = 0; i < 8; i++) { a0[i] = (short)h[i]; a1[i] = (short)h[8 + i]; }
        short8* dst = (short8*)(ybf + (size_t)(p0 + r) * NN + c);
        dst[0] = a0; dst[1] = a1;
        #pragma unroll
        for (int i = 0; i < 16; i++) tile[r][seg * 16 + i] = h[i];
    }
    // reduce squares within the 4 threads of a row (same wave: r = t>>2)
    s += __shfl_xor(s, 1);
    s += __shfl_xor(s, 2);
    if (seg == 0) atomicAdd(ws + WS_YY + p0 + r, s);
    __syncthreads();
    {
        const int cr = t >> 2, pseg = t & 3;
        const int cc = c0 + cr;
        if (cc < NN) {
            unsigned short h[16];
            #pragma unroll
            for (int i = 0; i < 16; i++) h[i] = tile[pseg * 16 + i][cr];
            short8 a0, a1;
            #pragma unroll
            for (int i = 0; i < 8; i++) { a0[i] = (short)h[i]; a1[i] = (short)h[8 + i]; }
            short8* dst = (short8*)(ybt + (size_t)cc * 512 + p0 + pseg * 16);
            dst[0] = a0; dst[1] = a1;
        }
    }
}

// ---------------- Gauss-Jordan 64x64 (augmented [64][128], stride 129), 1024 threads ----------------
__device__ inline void gj64(float (*aug)[129], float* prow, float* fac, int t) {
    for (int piv = 0; piv < 64; piv++) {
        if (t < 128) prow[t] = aug[piv][t];
        else if (t < 192) fac[t - 128] = aug[t - 128][piv];
        __syncthreads();
        float ip = 1.f / prow[piv];
        #pragma unroll
        for (int q = 0; q < 8; q++) {
            int o = t + q * 1024;
            int r = o >> 7, c = o & 127;
            float pv = prow[c] * ip;
            float v = aug[r][c];
            aug[r][c] = (r == piv) ? pv : v - fac[r] * pv;
        }
        __syncthreads();
    }
}

// ---------------- pre: psi_inv, A, Slog, M, (I+M)^-1, beta(bf16) ----------------
__global__ __launch_bounds__(1024) void k_pre(float* __restrict__ ws) {
    __shared__ char smraw[33280];   // union: aug[64][129] / Lc[128][65]
    __shared__ float pi[512];
    __shared__ float prow[128];
    __shared__ float fac[64];
    __shared__ float2 red[1024];
    float (*aug)[129] = (float (*)[129])smraw;
    float (*Lc)[65]   = (float (*)[65])smraw;
    const int t = threadIdx.x;

    if (t < 512) { float pv = ws[WS_PSI + t]; float iv = 1.f / pv; pi[t] = iv; ws[WS_PINV + t] = iv; }
    __syncthreads();

    float2 me = make_float2(0.f, 0.f);
    if (t < 512) { me.x = 0.5f * pi[t] * ws[WS_YY + t]; me.y = logf(ws[WS_PSI + t]); }
    red[t] = me;
    __syncthreads();
    for (int s = 512; s > 0; s >>= 1) {
        if (t < s) { red[t].x += red[t + s].x; red[t].y += red[t + s].y; }
        __syncthreads();
    }
    if (t == 0) { ws[WS_SCAL + 0] = red[0].x; ws[WS_SCAL + 1] = red[0].y; }

    // M = L^T diag(pi) L, staged in 4 chunks of 128 rows
    float macc[4] = {0.f, 0.f, 0.f, 0.f};
    for (int chk = 0; chk < 4; chk++) {
        __syncthreads();
        #pragma unroll
        for (int q = 0; q < 8; q++) { int o = t + q * 1024; Lc[o >> 6][o & 63] = ws[WS_L + chk * 8192 + o]; }
        __syncthreads();
        #pragma unroll
        for (int q = 0; q < 4; q++) {
            int o = t + q * 1024; int i = o >> 6, j = o & 63;
            float s = macc[q];
            for (int p = 0; p < 128; p++) s = fmaf(Lc[p][i] * pi[chk * 128 + p], Lc[p][j], s);
            macc[q] = s;
        }
    }
    __syncthreads();   // Lc dead -> safe to write aug (same memory)
    #pragma unroll
    for (int q = 0; q < 4; q++) {
        int o = t + q * 1024; int i = o >> 6, j = o & 63;
        ws[WS_M + o] = macc[q];
        aug[i][j] = macc[q] + ((i == j) ? 1.f : 0.f);
        aug[i][64 + j] = (i == j) ? 1.f : 0.f;
    }
    __syncthreads();
    gj64(aug, prow, fac, t);
    #pragma unroll
    for (int q = 0; q < 4; q++) { int o = t + q * 1024; ws[WS_IMINV + o] = aug[o >> 6][64 + (o & 63)]; }
    __syncthreads();   // IMinv saved -> aug space reusable as Lc

    // beta[kk][p] = pi[p] * sum_j IMinv[kk][j] * L[p][j]   -> bf16
    unsigned short* betabf = (unsigned short*)(ws + WS_BETA);
    for (int chk = 0; chk < 4; chk++) {
        #pragma unroll
        for (int q = 0; q < 8; q++) { int o = t + q * 1024; Lc[o >> 6][o & 63] = ws[WS_L + chk * 8192 + o]; }
        __syncthreads();
        #pragma unroll
        for (int q = 0; q < 8; q++) {
            int o = t + q * 1024;
            int kk = o >> 7, pl = o & 127;
            float s = 0.f;
            #pragma unroll 8
            for (int j = 0; j < 64; j++) s = fmaf(ws[WS_IMINV + kk * 64 + j], Lc[pl][j], s);
            int p = chk * 128 + pl;
            betabf[kk * 512 + p] = f2bf(s * pi[p]);
        }
        __syncthreads();
    }
}

// ---------------- big fused pass: Ez = beta*y ; G += Ez Ez^T ; LtermT += Ez (x) y ----------------
__global__ __launch_bounds__(512, 2) void k_big(float* __restrict__ ws) {
    __shared__ unsigned short ezb[64 * 40];   // Ez tile bf16, row stride 40 (80B, 5x16B slots)
    const unsigned short* betabf = (const unsigned short*)(ws + WS_BETA);
    const unsigned short* ybt    = (const unsigned short*)(ws + WS_YBT);
    const unsigned short* ybf    = (const unsigned short*)(ws + WS_YB);
    float* part = ws + WS_PART + (size_t)blockIdx.x * PART_STRIDE;

    const int t = threadIdx.x;
    const int w = t >> 6;
    const int l = t & 63;
    const int m16 = l & 15;
    const int g = l >> 4;
    const int mt = w >> 1, nt = w & 1;     // M1 roles: Ez tile (mt, nt)
    const int kkt = w & 3, ph = w >> 2;    // M3 roles

    // beta A-fragments, register-resident: rows 16*mt..+16, K = 512
    short8 bfr[16];
    #pragma unroll
    for (int ks = 0; ks < 16; ks++)
        bfr[ks] = *(const short8*)(betabf + (16 * mt + m16) * 512 + 32 * ks + 8 * g);

    float4v g_acc[2];
    float4v lt_acc[16];
    #pragma unroll
    for (int i = 0; i < 2; i++) g_acc[i] = (float4v){0.f, 0.f, 0.f, 0.f};
    #pragma unroll
    for (int i = 0; i < 16; i++) lt_acc[i] = (float4v){0.f, 0.f, 0.f, 0.f};

    for (int ch = blockIdx.x; ch < NCHUNK; ch += GRID_BIG) {
        const int c0 = ch * 32;
        // M1: Ez[16mt..+16][c0+16nt..+16] over K=512 (contract p, y^T operand)
        float4v ez = (float4v){0.f, 0.f, 0.f, 0.f};
        const unsigned short* yrow = ybt + (size_t)(c0 + 16 * nt + m16) * 512 + 8 * g;
        #pragma unroll
        for (int ks = 0; ks < 16; ks++) {
            short8 yf = *(const short8*)(yrow + 32 * ks);
            ez = __builtin_amdgcn_mfma_f32_16x16x32_bf16(bfr[ks], yf, ez, 0, 0, 0);
        }
        __syncthreads();   // prior chunk's ezb consumers done
        #pragma unroll
        for (int r = 0; r < 4; r++)
            ezb[(16 * mt + 4 * g + r) * 40 + 16 * nt + m16] = f2bf(ez[r]);
        __syncthreads();
        // M2: G tiles (it, jt) = (w>>1, 2*(w&1)+ti), contract over 32 cols
        short8 exi  = *(const short8*)(&ezb[(16 * (w >> 1) + m16) * 40 + 8 * g]);
        short8 eyj0 = *(const short8*)(&ezb[(16 * (2 * (w & 1)) + m16) * 40 + 8 * g]);
        short8 eyj1 = *(const short8*)(&ezb[(16 * (2 * (w & 1) + 1) + m16) * 40 + 8 * g]);
        g_acc[0] = __builtin_amdgcn_mfma_f32_16x16x32_bf16(exi, eyj0, g_acc[0], 0, 0, 0);
        g_acc[1] = __builtin_amdgcn_mfma_f32_16x16x32_bf16(exi, eyj1, g_acc[1], 0, 0, 0);
        // M3: LtermT[16kkt..+16][p-tiles], Y from global y_bf
        short8 exk = *(const short8*)(&ezb[(16 * kkt + m16) * 40 + 8 * g]);
        #pragma unroll
        for (int pt = 0; pt < 16; pt++) {
            const unsigned short* yp = ybf + (size_t)(256 * ph + 16 * pt + m16) * NN + (c0 + 8 * g);
            short8 yv = *(const short8*)yp;
            lt_acc[pt] = __builtin_amdgcn_mfma_f32_16x16x32_bf16(exk, yv, lt_acc[pt], 0, 0, 0);
        }
    }
    // epilogue: per-block partials (no atomics)
    #pragma unroll
    for (int ti = 0; ti < 2; ti++) {
        int it = w >> 1, jt = 2 * (w & 1) + ti;
        #pragma unroll
        for (int r = 0; r < 4; r++)
            part[(16 * it + 4 * g + r) * 64 + 16 * jt + m16] = g_acc[ti][r];
    }
    #pragma unroll
    for (int pt = 0; pt < 16; pt++) {
        int pr = 256 * ph + 16 * pt;
        #pragma unroll
        for (int r = 0; r < 4; r++)
            part[4096 + (16 * kkt + 4 * g + r) * 512 + pr + m16] = lt_acc[pt][r];
    }
}

// ---------------- reduce partials ----------------
__global__ __launch_bounds__(256) void k_reduce(float* __restrict__ ws) {
    int o = blockIdx.x * 256 + threadIdx.x;   // 0..36863
    float s = 0.f;
    #pragma unroll 4
    for (int b = 0; b < GRID_BIG; b++) s += ws[WS_PART + (size_t)b * PART_STRIDE + o];
    if (o < 4096) ws[WS_G + o] = s;
    else ws[WS_LT + o - 4096] = s;
}

// ---------------- post: Szz, nll, Szz^-1, Lambda_new, Psi_new, update/output ----------------
__global__ __launch_bounds__(1024) void k_post(float* __restrict__ ws, float* __restrict__ dout, int pass) {
    __shared__ char smraw[33280];
    float (*aug)[129] = (float (*)[129])smraw;
    __shared__ float prow[128];
    __shared__ float fac[64];
    __shared__ float2 red[1024];
    const int t = threadIdx.x;

    // Szz = n*(I+M)^-1 + G ; C-part = sum M.*Szz ; B-part
    float bp = 0.f, cp = 0.f;
    #pragma unroll
    for (int q = 0; q < 4; q++) {
        int o = t + q * 1024; int i = o >> 6, j = o & 63;
        float szz = (float)NN * ws[WS_IMINV + o] + ws[WS_G + o];
        aug[i][j] = szz;
        aug[i][64 + j] = (i == j) ? 1.f : 0.f;
        cp = fmaf(ws[WS_M + o], szz, cp);
    }
    #pragma unroll
    for (int q = 0; q < 32; q++) {
        int o = t + q * 1024; int k = o >> 9, p = o & 511;
        bp = fmaf(ws[WS_PINV + p] * ws[WS_L + p * 64 + k], ws[WS_LT + k * 512 + p], bp);
    }
    red[t] = make_float2(bp, cp);
    __syncthreads();
    for (int s = 512; s > 0; s >>= 1) {
        if (t < s) { red[t].x += red[t + s].x; red[t].y += red[t + s].y; }
        __syncthreads();
    }
    if (t == 0 && pass >= 1) {
        float A = ws[WS_SCAL + 0], Slog = ws[WS_SCAL + 1];
        dout[33280 + pass - 1] = A - red[0].x + 0.5f * red[0].y + 0.5f * (float)NN * Slog;
    }
    gj64(aug, prow, fac, t);
    // Lambda_new[p][kk] = sum_j LtermT[j][p] * SzzInv[j][kk]
    #pragma unroll
    for (int q = 0; q < 32; q++) {
        int o = t + q * 1024; int p = o >> 6, kk = o & 63;
        float s = 0.f;
        #pragma unroll 8
        for (int j = 0; j < 64; j++) s = fmaf(ws[WS_LT + j * 512 + p], aug[j][64 + kk], s);
        ws[WS_LNEW + o] = s;
    }
    __syncthreads();
    float psin = 0.f;
    if (t < 512) {
        float s = 0.f;
        #pragma unroll 8
        for (int k = 0; k < 64; k++) s = fmaf(ws[WS_LNEW + t * 64 + k], ws[WS_LT + k * 512 + t], s);
        psin = (ws[WS_YY + t] - s) * (1.f / (float)NN);
    }
    __syncthreads();
    if (pass < 8) {
        #pragma unroll
        for (int q = 0; q < 32; q++) { int o = t + q * 1024; ws[WS_L + o] = ws[WS_LNEW + o]; }
        if (t < 512) ws[WS_PSI + t] = psin;
    } else {
        #pragma unroll
        for (int q = 0; q < 32; q++) { int o = t + q * 1024; dout[o] = ws[WS_L + o]; }
        if (t < 512) dout[32768 + t] = ws[WS_PSI + t];
    }
}

extern "C" void kernel_launch(void* const* d_in, const int* in_sizes, int n_in,
                              void* d_out, int out_size, void* d_ws, size_t ws_size,
                              hipStream_t stream) {
    const float* y  = (const float*)d_in[0];
    const float* l1 = (const float*)d_in[1];
    const float* l2 = (const float*)d_in[2];
    const float* p1 = (const float*)d_in[3];
    const float* p2 = (const float*)d_in[4];
    float* out = (float*)d_out;
    float* ws  = (float*)d_ws;

    if (ws_size < WS_TOTAL_F * sizeof(float)) return;   // signal via absmax failure rather than fault

    hipMemsetAsync(ws + WS_YY, 0, 512 * sizeof(float), stream);
    k_init<<<130, 256, 0, stream>>>(l1, l2, p1, p2, ws);
    k_convert<<<dim3(1563, 8), 256, 0, stream>>>(y, ws);
    for (int pass = 0; pass <= 8; pass++) {
        k_pre<<<1, 1024, 0, stream>>>(ws);
        k_big<<<GRID_BIG, 512, 0, stream>>>(ws);
        k_reduce<<<144, 256, 0, stream>>>(ws);
        k_post<<<1, 1024, 0, stream>>>(ws, out, pass);
    }
}

// Round 5
// 3385.006 us; speedup vs baseline: 1.5420x; 1.5420x over previous
//
#include <hip/hip_runtime.h>
#include <hip/hip_bf16.h>

typedef __attribute__((ext_vector_type(8))) short short8;
typedef __attribute__((ext_vector_type(4))) float float4v;

#define NN 100000
#define NCHUNK 3125          // NN / 32
#define GRID_BIG 255
#define PART_STRIDE (4096 + 32768)

// workspace layout (float offsets)
#define WS_L      0          // [512][64] f32
#define WS_LR     32768      // [64][512] f32 (transposed L)
#define WS_PSI    65536
#define WS_PINV   66048
#define WS_YY     66560
#define WS_M      67072      // [64][64]
#define WS_IMINV  71168      // [64][64]
#define WS_G      75264      // [64][64]
#define WS_LT     79360      // LtermT [64][512]
#define WS_SZI    112128     // SzzInv [64][64]
#define WS_SCAL   116224     // 0=A,1=Slog,2=bp,3=cp
#define WS_BETA   116240     // bf16 [64][512] = 16384 float slots -> ends 132624
#define WS_PART   132624     // 255 * 36864 -> ends 9532944
#define WS_MPART  9532944    // 8 * 4096 -> ends 9565712
#define WS_YBT    9565952    // bf16 [100000][512]
#define WS_YB     35165952   // bf16 [512][100000]
#define WS_TOTAL_F 60765952ULL

__device__ inline unsigned short f2bf(float f) {
    unsigned int u = __float_as_uint(f);
    u = u + 0x7FFFu + ((u >> 16) & 1u);
    return (unsigned short)(u >> 16);
}

// ---------------- init: L, Lr, Psi ----------------
__global__ void k_init(const float* __restrict__ l1, const float* __restrict__ l2,
                       const float* __restrict__ p1, const float* __restrict__ p2,
                       float* __restrict__ ws) {
    int i = blockIdx.x * 256 + threadIdx.x;
    if (i < 16384) {
        float v = l1[i];
        ws[WS_L + i] = v;
        ws[WS_LR + (i & 63) * 512 + (i >> 6)] = v;
    } else if (i < 32768) {
        float v = l2[i - 16384];
        ws[WS_L + i] = v;
        ws[WS_LR + (i & 63) * 512 + (i >> 6)] = v;
    } else if (i < 33280) {
        int j = i - 32768;
        ws[WS_PSI + j] = (j < 256) ? p1[j] : p2[j - 256];
    }
}

// ---------------- convert: y f32 -> y_bf (p-major) + y_bfT (n-major), yy_sum ----------------
__global__ __launch_bounds__(256) void k_convert(const float* __restrict__ y, float* __restrict__ ws) {
    __shared__ unsigned short tile[64][65];
    const int t = threadIdx.x;
    const int c0 = blockIdx.x * 64;
    const int p0 = blockIdx.y * 64;
    unsigned short* ybf = (unsigned short*)(ws + WS_YB);
    unsigned short* ybt = (unsigned short*)(ws + WS_YBT);

    const int r = t >> 2, seg = t & 3;
    const int c = c0 + seg * 16;
    float s = 0.f;
    if (c < NN) {
        const float* src = y + (size_t)(p0 + r) * NN + c;
        float v[16];
        #pragma unroll
        for (int i = 0; i < 16; i++) v[i] = src[i];
        unsigned short h[16];
        #pragma unroll
        for (int i = 0; i < 16; i++) { s = fmaf(v[i], v[i], s); h[i] = f2bf(v[i]); }
        short8 a0, a1;
        #pragma unroll
        for (int i = 0; i < 8; i++) { a0[i] = (short)h[i]; a1[i] = (short)h[8 + i]; }
        short8* dst = (short8*)(ybf + (size_t)(p0 + r) * NN + c);
        dst[0] = a0; dst[1] = a1;
        #pragma unroll
        for (int i = 0; i < 16; i++) tile[r][seg * 16 + i] = h[i];
    }
    s += __shfl_xor(s, 1);
    s += __shfl_xor(s, 2);
    if (seg == 0) atomicAdd(ws + WS_YY + p0 + r, s);
    __syncthreads();
    {
        const int cr = t >> 2, pseg = t & 3;
        const int cc = c0 + cr;
        if (cc < NN) {
            unsigned short h[16];
            #pragma unroll
            for (int i = 0; i < 16; i++) h[i] = tile[pseg * 16 + i][cr];
            short8 a0, a1;
            #pragma unroll
            for (int i = 0; i < 8; i++) { a0[i] = (short)h[i]; a1[i] = (short)h[8 + i]; }
            short8* dst = (short8*)(ybt + (size_t)cc * 512 + p0 + pseg * 16);
            dst[0] = a0; dst[1] = a1;
        }
    }
}

// ---------------- Gauss-Jordan 64x64, 512 threads ----------------
__device__ inline void gj64_512(float (*aug)[129], float* prow, float* fac, int t) {
    for (int piv = 0; piv < 64; piv++) {
        if (t < 128) prow[t] = aug[piv][t];
        else if (t < 192) fac[t - 128] = aug[t - 128][piv];
        __syncthreads();
        float ip = 1.f / prow[piv];
        #pragma unroll
        for (int q = 0; q < 16; q++) {
            int o = t + q * 512;
            int r = o >> 7, c = o & 127;
            float pv = prow[c] * ip;
            float v = aug[r][c];
            aug[r][c] = (r == piv) ? pv : v - fac[r] * pv;
        }
        __syncthreads();
    }
}

// ---------------- shared: per-64p-block M partial from g = sqrt(pi)*L rows ----------------
__device__ inline void partial_M(const float (*g)[68], int t, float* __restrict__ dst) {
    const int i2 = t & 63, w8 = t >> 6;   // i2 = row i, w8 = j-octet
    float macc[8] = {0.f, 0.f, 0.f, 0.f, 0.f, 0.f, 0.f, 0.f};
    #pragma unroll 8
    for (int p = 0; p < 64; p++) {
        float a = g[p][i2];
        float4 b0 = *(const float4*)&g[p][8 * w8];
        float4 b1 = *(const float4*)&g[p][8 * w8 + 4];
        macc[0] = fmaf(a, b0.x, macc[0]); macc[1] = fmaf(a, b0.y, macc[1]);
        macc[2] = fmaf(a, b0.z, macc[2]); macc[3] = fmaf(a, b0.w, macc[3]);
        macc[4] = fmaf(a, b1.x, macc[4]); macc[5] = fmaf(a, b1.y, macc[5]);
        macc[6] = fmaf(a, b1.z, macc[6]); macc[7] = fmaf(a, b1.w, macc[7]);
    }
    float4 s0 = make_float4(macc[0], macc[1], macc[2], macc[3]);
    float4 s1 = make_float4(macc[4], macc[5], macc[6], macc[7]);
    *(float4*)&dst[i2 * 64 + 8 * w8] = s0;
    *(float4*)&dst[i2 * 64 + 8 * w8 + 4] = s1;
}

// ---------------- m0: seed M-partials from initial params ----------------
__global__ __launch_bounds__(512) void k_m0(float* __restrict__ ws) {
    __shared__ float g[64][68];
    const int t = threadIdx.x, b = blockIdx.x;
    const int pl = t >> 3, oct = t & 7;
    const int p = 64 * b + pl;
    float rs = rsqrtf(fmaxf(ws[WS_PSI + p], 1e-8f));
    float4 v0 = *(const float4*)&ws[WS_L + p * 64 + oct * 8];
    float4 v1 = *(const float4*)&ws[WS_L + p * 64 + oct * 8 + 4];
    g[pl][oct * 8 + 0] = rs * v0.x; g[pl][oct * 8 + 1] = rs * v0.y;
    g[pl][oct * 8 + 2] = rs * v0.z; g[pl][oct * 8 + 3] = rs * v0.w;
    g[pl][oct * 8 + 4] = rs * v1.x; g[pl][oct * 8 + 5] = rs * v1.y;
    g[pl][oct * 8 + 6] = rs * v1.z; g[pl][oct * 8 + 7] = rs * v1.w;
    __syncthreads();
    partial_M(g, t, ws + WS_MPART + b * 4096);
}

// ---------------- pre: pi, A, Slog, M-sum, (I+M)^-1, beta via MFMA ----------------
__global__ __launch_bounds__(512) void k_pre(float* __restrict__ ws) {
    __shared__ float aug[64][129];
    __shared__ unsigned short imb[64 * 64];
    __shared__ float pi[512];
    __shared__ float prow[128];
    __shared__ float fac[64];
    __shared__ float2 red[512];
    const int t = threadIdx.x;

    float pv = ws[WS_PSI + t];
    float iv = 1.f / pv;
    pi[t] = iv; ws[WS_PINV + t] = iv;
    if (t == 0) { ws[WS_SCAL + 2] = 0.f; ws[WS_SCAL + 3] = 0.f; }
    red[t] = make_float2(0.5f * iv * ws[WS_YY + t], logf(pv));

    // M = sum of 8 partials; build aug
    #pragma unroll
    for (int q = 0; q < 8; q++) {
        int o = t + 512 * q;
        float m = 0.f;
        #pragma unroll
        for (int b = 0; b < 8; b++) m += ws[WS_MPART + b * 4096 + o];
        int i = o >> 6, j = o & 63;
        ws[WS_M + o] = m;
        aug[i][j] = m + ((i == j) ? 1.f : 0.f);
        aug[i][64 + j] = (i == j) ? 1.f : 0.f;
    }
    __syncthreads();
    // A/Slog reduction
    for (int st = 256; st > 0; st >>= 1) {
        if (t < st) { red[t].x += red[t + st].x; red[t].y += red[t + st].y; }
        __syncthreads();
    }
    if (t == 0) { ws[WS_SCAL + 0] = red[0].x; ws[WS_SCAL + 1] = red[0].y; }

    gj64_512(aug, prow, fac, t);
    #pragma unroll
    for (int q = 0; q < 8; q++) {
        int o = t + 512 * q;
        float v = aug[o >> 6][64 + (o & 63)];
        ws[WS_IMINV + o] = v;
        imb[o] = f2bf(v);
    }
    __syncthreads();

    // beta = (I+M)^-1 L^T diag(pi) via MFMA: D[kk][p], then *pi[p] -> bf16
    // B-frags read L straight from global (L2-resident, 128KB) with on-the-fly bf16 convert.
    unsigned short* betabf = (unsigned short*)(ws + WS_BETA);
    const int w = t >> 6, l = t & 63, m16 = l & 15, g4 = l >> 4;
    for (int n = 0; n < 16; n++) {
        int tau = w * 16 + n;
        int kt = tau >> 5, pt = tau & 31;    // 4 kk-tiles x 32 p-tiles = 128 tiles
        float4v acc = (float4v){0.f, 0.f, 0.f, 0.f};
        #pragma unroll
        for (int ks = 0; ks < 2; ks++) {
            short8 af = *(const short8*)&imb[(16 * kt + m16) * 64 + 32 * ks + 8 * g4];
            const float* lp = ws + WS_L + (16 * pt + m16) * 64 + 32 * ks + 8 * g4;
            float4 f0 = *(const float4*)lp;
            float4 f1 = *(const float4*)(lp + 4);
            short8 bf;
            bf[0] = (short)f2bf(f0.x); bf[1] = (short)f2bf(f0.y);
            bf[2] = (short)f2bf(f0.z); bf[3] = (short)f2bf(f0.w);
            bf[4] = (short)f2bf(f1.x); bf[5] = (short)f2bf(f1.y);
            bf[6] = (short)f2bf(f1.z); bf[7] = (short)f2bf(f1.w);
            acc = __builtin_amdgcn_mfma_f32_16x16x32_bf16(af, bf, acc, 0, 0, 0);
        }
        int p = 16 * pt + m16;
        float piv_ = pi[p];
        #pragma unroll
        for (int r = 0; r < 4; r++) {
            int kk = 16 * kt + 4 * g4 + r;
            betabf[kk * 512 + p] = f2bf(acc[r] * piv_);
        }
    }
}

// ---------------- big fused pass: Ez = beta*y ; G += Ez Ez^T ; LtermT += Ez (x) y ----------------
__global__ __launch_bounds__(512, 2) void k_big(float* __restrict__ ws) {
    __shared__ unsigned short ezb[64 * 40];
    const unsigned short* betabf = (const unsigned short*)(ws + WS_BETA);
    const unsigned short* ybt    = (const unsigned short*)(ws + WS_YBT);
    const unsigned short* ybf    = (const unsigned short*)(ws + WS_YB);
    float* part = ws + WS_PART + (size_t)blockIdx.x * PART_STRIDE;

    const int t = threadIdx.x;
    const int w = t >> 6;
    const int l = t & 63;
    const int m16 = l & 15;
    const int g = l >> 4;
    const int mt = w >> 1, nt = w & 1;
    const int kkt = w & 3, ph = w >> 2;

    short8 bfr[16];
    #pragma unroll
    for (int ks = 0; ks < 16; ks++)
        bfr[ks] = *(const short8*)(betabf + (16 * mt + m16) * 512 + 32 * ks + 8 * g);

    float4v g_acc[2];
    float4v lt_acc[16];
    #pragma unroll
    for (int i = 0; i < 2; i++) g_acc[i] = (float4v){0.f, 0.f, 0.f, 0.f};
    #pragma unroll
    for (int i = 0; i < 16; i++) lt_acc[i] = (float4v){0.f, 0.f, 0.f, 0.f};

    for (int ch = blockIdx.x; ch < NCHUNK; ch += GRID_BIG) {
        const int c0 = ch * 32;
        float4v ez = (float4v){0.f, 0.f, 0.f, 0.f};
        const unsigned short* yrow = ybt + (size_t)(c0 + 16 * nt + m16) * 512 + 8 * g;
        #pragma unroll
        for (int ks = 0; ks < 16; ks++) {
            short8 yf = *(const short8*)(yrow + 32 * ks);
            ez = __builtin_amdgcn_mfma_f32_16x16x32_bf16(bfr[ks], yf, ez, 0, 0, 0);
        }
        __syncthreads();
        #pragma unroll
        for (int r = 0; r < 4; r++)
            ezb[(16 * mt + 4 * g + r) * 40 + 16 * nt + m16] = f2bf(ez[r]);
        __syncthreads();
        short8 exi  = *(const short8*)(&ezb[(16 * (w >> 1) + m16) * 40 + 8 * g]);
        short8 eyj0 = *(const short8*)(&ezb[(16 * (2 * (w & 1)) + m16) * 40 + 8 * g]);
        short8 eyj1 = *(const short8*)(&ezb[(16 * (2 * (w & 1) + 1) + m16) * 40 + 8 * g]);
        g_acc[0] = __builtin_amdgcn_mfma_f32_16x16x32_bf16(exi, eyj0, g_acc[0], 0, 0, 0);
        g_acc[1] = __builtin_amdgcn_mfma_f32_16x16x32_bf16(exi, eyj1, g_acc[1], 0, 0, 0);
        short8 exk = *(const short8*)(&ezb[(16 * kkt + m16) * 40 + 8 * g]);
        #pragma unroll
        for (int pt = 0; pt < 16; pt++) {
            const unsigned short* yp = ybf + (size_t)(256 * ph + 16 * pt + m16) * NN + (c0 + 8 * g);
            short8 yv = *(const short8*)yp;
            lt_acc[pt] = __builtin_amdgcn_mfma_f32_16x16x32_bf16(exk, yv, lt_acc[pt], 0, 0, 0);
        }
    }
    #pragma unroll
    for (int ti = 0; ti < 2; ti++) {
        int it = w >> 1, jt = 2 * (w & 1) + ti;
        #pragma unroll
        for (int r = 0; r < 4; r++)
            part[(16 * it + 4 * g + r) * 64 + 16 * jt + m16] = g_acc[ti][r];
    }
    #pragma unroll
    for (int pt = 0; pt < 16; pt++) {
        int pr = 256 * ph + 16 * pt;
        #pragma unroll
        for (int r = 0; r < 4; r++)
            part[4096 + (16 * kkt + 4 * g + r) * 512 + pr + m16] = lt_acc[pt][r];
    }
}

// ---------------- reduce partials + bp/cp (nll B,C) ----------------
__global__ __launch_bounds__(256) void k_reduce(float* __restrict__ ws) {
    __shared__ float rsum[256];
    const int tt = threadIdx.x;
    int o = blockIdx.x * 256 + tt;
    float s = 0.f;
    #pragma unroll 4
    for (int b = 0; b < GRID_BIG; b++) s += ws[WS_PART + (size_t)b * PART_STRIDE + o];
    float contrib;
    if (o < 4096) {
        ws[WS_G + o] = s;
        contrib = ws[WS_M + o] * ((float)NN * ws[WS_IMINV + o] + s);   // cp part
    } else {
        int oo = o - 4096;
        ws[WS_LT + oo] = s;
        contrib = ws[WS_PINV + (oo & 511)] * ws[WS_LR + oo] * s;       // bp part
    }
    rsum[tt] = contrib;
    __syncthreads();
    for (int st = 128; st > 0; st >>= 1) {
        if (tt < st) rsum[tt] += rsum[tt + st];
        __syncthreads();
    }
    if (tt == 0) atomicAdd(ws + WS_SCAL + ((o < 4096) ? 3 : 2), rsum[0]);
}

// ---------------- post: nll finalize, Szz, Szz^-1 ----------------
__global__ __launch_bounds__(512) void k_post(float* __restrict__ ws, float* __restrict__ dout, int pass) {
    __shared__ float aug[64][129];
    __shared__ float prow[128];
    __shared__ float fac[64];
    const int t = threadIdx.x;

    if (t == 0 && pass >= 1) {
        float A = ws[WS_SCAL + 0], Slog = ws[WS_SCAL + 1];
        float bp = ws[WS_SCAL + 2], cp = ws[WS_SCAL + 3];
        dout[33280 + pass - 1] = A - bp + 0.5f * cp + 0.5f * (float)NN * Slog;
    }
    if (pass == 8) return;   // no update needed after last nll

    #pragma unroll
    for (int q = 0; q < 8; q++) {
        int o = t + 512 * q;
        int i = o >> 6, j = o & 63;
        aug[i][j] = (float)NN * ws[WS_IMINV + o] + ws[WS_G + o];
        aug[i][64 + j] = (i == j) ? 1.f : 0.f;
    }
    __syncthreads();
    gj64_512(aug, prow, fac, t);
    #pragma unroll
    for (int q = 0; q < 8; q++) {
        int o = t + 512 * q;
        ws[WS_SZI + o] = aug[o >> 6][64 + (o & 63)];
    }
}

// ---------------- upd: Lambda_new, Psi_new, L/Lr/Psi update, next-pass M partials ----------------
__global__ __launch_bounds__(512) void k_upd(float* __restrict__ ws, float* __restrict__ dout, int pass) {
    __shared__ float szi[64][68];   // SzzInv, later reused as g
    __shared__ float lt[64][66];    // LT block [j][p_local]
    const int t = threadIdx.x, b = blockIdx.x;
    const int p0 = 64 * b;
    const int pl = t >> 3, oct = t & 7;
    const int p = p0 + pl;

    if (pass == 8) {   // copy-out final params
        float4 v0 = *(const float4*)&ws[WS_L + p * 64 + oct * 8];
        float4 v1 = *(const float4*)&ws[WS_L + p * 64 + oct * 8 + 4];
        *(float4*)&dout[p * 64 + oct * 8] = v0;
        *(float4*)&dout[p * 64 + oct * 8 + 4] = v1;
        if (oct == 0) dout[32768 + p] = ws[WS_PSI + p];
        return;
    }

    #pragma unroll
    for (int q = 0; q < 8; q++) { int o = t + 512 * q; szi[o >> 6][o & 63] = ws[WS_SZI + o]; }
    #pragma unroll
    for (int q = 0; q < 8; q++) { int o = t + 512 * q; lt[o >> 6][o & 63] = ws[WS_LT + (o >> 6) * 512 + p0 + (o & 63)]; }
    __syncthreads();

    float acc[8] = {0.f, 0.f, 0.f, 0.f, 0.f, 0.f, 0.f, 0.f};
    #pragma unroll
    for (int j = 0; j < 64; j++) {
        float ltv = lt[j][pl];
        float4 s0 = *(const float4*)&szi[j][oct * 8];
        float4 s1 = *(const float4*)&szi[j][oct * 8 + 4];
        acc[0] = fmaf(ltv, s0.x, acc[0]); acc[1] = fmaf(ltv, s0.y, acc[1]);
        acc[2] = fmaf(ltv, s0.z, acc[2]); acc[3] = fmaf(ltv, s0.w, acc[3]);
        acc[4] = fmaf(ltv, s1.x, acc[4]); acc[5] = fmaf(ltv, s1.y, acc[5]);
        acc[6] = fmaf(ltv, s1.z, acc[6]); acc[7] = fmaf(ltv, s1.w, acc[7]);
    }
    // psin = (YY - sum_k Lnew[p,k]*LT[k,p]) / n  via 8-lane partial + shfl
    float psum = 0.f;
    #pragma unroll
    for (int i = 0; i < 8; i++) psum = fmaf(acc[i], lt[oct * 8 + i][pl], psum);
    psum += __shfl_xor(psum, 1);
    psum += __shfl_xor(psum, 2);
    psum += __shfl_xor(psum, 4);
    float psin = (ws[WS_YY + p] - psum) * (1.f / (float)NN);

    // update L (p-major + transposed) and Psi
    float4 a0 = make_float4(acc[0], acc[1], acc[2], acc[3]);
    float4 a1 = make_float4(acc[4], acc[5], acc[6], acc[7]);
    *(float4*)&ws[WS_L + p * 64 + oct * 8] = a0;
    *(float4*)&ws[WS_L + p * 64 + oct * 8 + 4] = a1;
    #pragma unroll
    for (int i = 0; i < 8; i++) ws[WS_LR + (oct * 8 + i) * 512 + p] = acc[i];
    if (oct == 0) ws[WS_PSI + p] = psin;

    // next-pass M partial: g = sqrt(1/psin) * Lnew rows (reuse szi)
    float rs = rsqrtf(fmaxf(psin, 1e-8f));
    __syncthreads();   // all szi/lt reads done
    #pragma unroll
    for (int i = 0; i < 8; i++) szi[pl][oct * 8 + i] = rs * acc[i];
    __syncthreads();
    partial_M(szi, t, ws + WS_MPART + b * 4096);
}

extern "C" void kernel_launch(void* const* d_in, const int* in_sizes, int n_in,
                              void* d_out, int out_size, void* d_ws, size_t ws_size,
                              hipStream_t stream) {
    const float* y  = (const float*)d_in[0];
    const float* l1 = (const float*)d_in[1];
    const float* l2 = (const float*)d_in[2];
    const float* p1 = (const float*)d_in[3];
    const float* p2 = (const float*)d_in[4];
    float* out = (float*)d_out;
    float* ws  = (float*)d_ws;

    if (ws_size < WS_TOTAL_F * sizeof(float)) return;

    hipMemsetAsync(ws + WS_YY, 0, 512 * sizeof(float), stream);
    k_init<<<130, 256, 0, stream>>>(l1, l2, p1, p2, ws);
    k_convert<<<dim3(1563, 8), 256, 0, stream>>>(y, ws);
    k_m0<<<8, 512, 0, stream>>>(ws);
    for (int pass = 0; pass <= 8; pass++) {
        k_pre<<<1, 512, 0, stream>>>(ws);
        k_big<<<GRID_BIG, 512, 0, stream>>>(ws);
        k_reduce<<<144, 256, 0, stream>>>(ws);
        k_post<<<1, 512, 0, stream>>>(ws, out, pass);
        k_upd<<<8, 512, 0, stream>>>(ws, out, pass);
    }
}